// Round 15
// baseline (339.720 us; speedup 1.0000x reference)
//
#include <hip/hip_runtime.h>

#define N_NODES 100000
#define N_EDGES 1600000
#define N_GRAPHS 512
#define HID 64
#define NUM_CLASSES 100
#define ID_OFFSET 1500
#define BN_EPS 1e-5f
#define CAP 64
#define NBKT 256
#define BSHIFT 9
#define NUSED ((N_NODES + 511) >> 9)   // 196 buckets of 512 nodes
#define BCAP 10240                      // per-bucket record capacity
#define CBLK 98
#define CHUNK 16384
#define WPBLK 5                         // wprep blocks inside prep_kernel
#define EMBBLK ((N_NODES * 32 + 1023) / 1024)   // 3125
#define SREP 32                         // stats atomic replicas (chain 1563/32 ~ 49)
#define SSTRIDE 384                     // floats per stats replica
#define ZWORDS (98304 + SREP * SSTRIDE + 100000)  // pooled + stats + cnt (4B words)
#define ZBLK ((ZWORDS + 1023) / 1024)   // zero blocks inside prep
#define DUMMY_ROW 100000                // zeroed row in x-buffer slack, pad target

typedef __attribute__((ext_vector_type(8))) short short8;
typedef __attribute__((ext_vector_type(4))) float floatx4;

__device__ __forceinline__ float b2f(unsigned short u) {
    return __builtin_bit_cast(float, ((unsigned)u) << 16);
}
__device__ __forceinline__ unsigned short f2b(float f) {   // RNE
    unsigned x = __builtin_bit_cast(unsigned, f);
    x += 0x7FFFu + ((x >> 16) & 1u);
    return (unsigned short)(x >> 16);
}

// swizzled granule layout: 16-row tiles, 8 granules(16B)/row, granule slot = (row&15)^q
#define XSH(row, qq) ((((((row) >> 4) << 7) + ((qq) << 4) + (((row) & 15) ^ (qq))) * 8))

// ---------------- fused prep: binning + wprep + embed + workspace zero ----------------

__global__ __launch_bounds__(1024) void prep_kernel(const int* __restrict__ src,
                                                    const int* __restrict__ dst,
                                                    int* __restrict__ cursor,
                                                    int* __restrict__ rec,
                                                    const float* __restrict__ Ws,
                                                    unsigned short* __restrict__ whi,
                                                    unsigned short* __restrict__ wlo,
                                                    const int* __restrict__ node_ids,
                                                    const int* __restrict__ gid,
                                                    const float* __restrict__ emb,
                                                    unsigned short* __restrict__ h,
                                                    unsigned short* __restrict__ xin,
                                                    int* __restrict__ gs,
                                                    int* __restrict__ ge,
                                                    unsigned* __restrict__ zbase) {
    __shared__ int hist[NBKT];
    __shared__ int base_s[NBKT];
    int t = threadIdx.x;
    int blk = blockIdx.x;

    if (blk < CBLK) {
        // ---- dummy-row zeroing piggybacked on block 0 (replaces 2 memset launches)
        if (blk == 0 && t < 32) {
            ((unsigned*)(h + (size_t)DUMMY_ROW * 64))[t] = 0u;
            ((unsigned*)(xin + (size_t)DUMMY_ROW * 64))[t] = 0u;
        }
        // ---- edge binning (one pass) ----
        if (t < NBKT) hist[t] = 0;
        __syncthreads();
        int cb = blk * CHUNK;
        int d_[16], s_[16];
#pragma unroll
        for (int k = 0; k < 16; ++k) {
            int i = cb + k * 1024 + t;
            d_[k] = (i < N_EDGES) ? dst[i] : -1;
            s_[k] = (i < N_EDGES) ? src[i] : 0;
            if (d_[k] >= 0) atomicAdd(&hist[((unsigned)d_[k] >> BSHIFT) & (NBKT - 1)], 1);
        }
        __syncthreads();
        if (t < NBKT) base_s[t] = (hist[t] > 0) ? atomicAdd(&cursor[t], hist[t]) : 0;
        __syncthreads();
        if (t < NBKT) hist[t] = 0;
        __syncthreads();
#pragma unroll
        for (int k = 0; k < 16; ++k) {
            if (d_[k] >= 0) {
                unsigned d = (unsigned)d_[k];
                int b = (d >> BSHIFT) & (NBKT - 1);
                int p = atomicAdd(&hist[b], 1);
                int g = base_s[b] + p;
                if ((unsigned)g < BCAP)
                    rec[b * BCAP + g] = ((int)(d & 511) << 17) | (s_[k] & 0x1FFFF);
            }
        }
    } else if (blk < CBLK + WPBLK) {
        // ---- W pre-convert + pre-swizzle, hi/lo split ----
        int G = (blk - CBLK) * 1024 + t;
        if (G < 3 * 1536) {
            int l = G / 1536, Gp = G % 1536;
            int mm = Gp >> 9, rem = Gp & 511;
            int kq = rem >> 6, n = rem & 63;
            const float* Wp = Ws + l * 12288 + mm * 4096 + (kq * 8) * 64 + n;
            unsigned short uh[8], ul[8];
#pragma unroll
            for (int j = 0; j < 8; ++j) {
                float w = Wp[j * 64];
                unsigned short hi = f2b(w);
                uh[j] = hi;
                ul[j] = f2b(w - b2f(hi));
            }
            size_t off = (size_t)l * 12288 + (mm << 12) + XSH(n, kq);
            *(short8*)&whi[off] = *(short8*)uh;
            *(short8*)&wlo[off] = *(short8*)ul;
        }
    } else if (blk < CBLK + WPBLK + EMBBLK) {
        // ---- embedding gather (bf16) + sorted-graph span boundaries ----
        int idx = (blk - CBLK - WPBLK) * 1024 + t;
        if (idx < N_NODES * 32) {
            int n = idx >> 5, cp = idx & 31;
            const float2 e = *(const float2*)(emb + (((size_t)(node_ids[n] + ID_OFFSET)) << 6) + cp * 2);
            unsigned v = (unsigned)f2b(e.x) | ((unsigned)f2b(e.y) << 16);
            ((unsigned*)h)[n * 32 + cp] = v;
            if (cp == 0) {
                int g = gid[n] & (N_GRAPHS - 1);
                if (n == 0 || (gid[n - 1] & (N_GRAPHS - 1)) != g) gs[g] = n;
                if (n == N_NODES - 1 || (gid[n + 1] & (N_GRAPHS - 1)) != g) ge[g] = n + 1;
            }
        }
    } else {
        // ---- zero pooled + stats + cnt (consumers run in later kernels)
        int idx = (blk - CBLK - WPBLK - EMBBLK) * 1024 + t;
        if (idx < ZWORDS) zbase[idx] = 0u;
    }
}

// ---------------- per-bucket CSR fill (block-parallel pad to multiple of 16) ----------------

__global__ __launch_bounds__(1024) void fill_kernel(const int* __restrict__ rec,
                                                    const int* __restrict__ cursor,
                                                    int* __restrict__ cnt,
                                                    int* __restrict__ srcs) {
    __shared__ int lcnt[512];
    int t = threadIdx.x;
    int b = blockIdx.x;            // 0..NUSED-1
    if (t < 512) lcnt[t] = 0;
    __syncthreads();
    int nb = cursor[b];
    if (nb < 0) nb = 0;
    if (nb > BCAP) nb = BCAP;
    const int* seg = rec + b * BCAP;
    for (int i = t; i < nb; i += 1024) {
        unsigned r = (unsigned)seg[i];
        int dl = (int)((r >> 17) & 511);
        int s = (int)(r & 0x1FFFF);
        int node = (b << BSHIFT) + dl;
        int p = atomicAdd(&lcnt[dl], 1);
        if (p < CAP && node < N_NODES) srcs[(node << 6) + p] = s;
    }
    __syncthreads();
    if (t < 512) {
        int node = (b << BSHIFT) + t;
        if (node < N_NODES) cnt[node] = lcnt[t];
    }
    __syncthreads();
    // block-parallel padding: slot p of node nl gets DUMMY if degc <= p < degp
    for (int i = t; i < 512 * 64; i += 1024) {
        int nl = i >> 6, p = i & 63;
        int node = (b << BSHIFT) + nl;
        if (node < N_NODES) {
            int deg = lcnt[nl];
            int degc = deg > CAP ? CAP : deg;
            int degp = (degc + 15) & ~15;
            if (degp < 16) degp = 16;
            if (p >= degc && p < degp) srcs[(node << 6) + p] = DUMMY_ROW;
        }
    }
}

// ---------------- GIN aggregation (frozen: proven 2.15 TB/s; SREP-summed BN) ----------------

__global__ __launch_bounds__(256) void agg_kernel(const unsigned short* __restrict__ x,
                                                  const int* __restrict__ cnt,
                                                  const int* __restrict__ srcs,
                                                  const float* __restrict__ eps, int l,
                                                  const float* __restrict__ stats,
                                                  const float* __restrict__ gamma,
                                                  const float* __restrict__ beta,
                                                  unsigned short* __restrict__ out) {
    int nb = __builtin_amdgcn_readfirstlane(((blockIdx.x << 2) + (threadIdx.x >> 6)) << 2);
    int lane = threadIdx.x & 63;
    int half = lane >> 5;
    int cl = lane & 31;
    const unsigned* __restrict__ xu = (const unsigned*)x;

    // ---- BN coefficients for layer l-1 (replica-summed), prefetched early
    float scale = 1.0f + eps[l];
    float a0f = 1.0f, a1f = 1.0f, b0f = 0.0f, b1f = 0.0f;
    if (l > 0) {
        int lp = l - 1;
        float sm0 = 0.f, sm1 = 0.f, sq0 = 0.f, sq1 = 0.f;
#pragma unroll
        for (int rp = 0; rp < SREP; ++rp) {
            const float* sp = stats + rp * SSTRIDE + lp * 128;
            float2 a_ = *(const float2*)&sp[2 * cl];
            float2 b_ = *(const float2*)&sp[64 + 2 * cl];
            sm0 += a_.x; sm1 += a_.y;
            sq0 += b_.x; sq1 += b_.y;
        }
        float2 gm = *(const float2*)&gamma[lp * 64 + 2 * cl];
        float2 bt = *(const float2*)&beta[lp * 64 + 2 * cl];
        float mean0 = sm0 * (1.0f / N_NODES);
        float var0 = sq0 * (1.0f / N_NODES) - mean0 * mean0;
        float r0 = rsqrtf(var0 + BN_EPS);
        a0f = gm.x * r0;
        b0f = bt.x - mean0 * a0f;
        float mean1 = sm1 * (1.0f / N_NODES);
        float var1 = sq1 * (1.0f / N_NODES) - mean1 * mean1;
        float r1 = rsqrtf(var1 + BN_EPS);
        a1f = gm.y * r1;
        b1f = bt.y - mean1 * a1f;
    }

    // ---- degrees + row pointers for 4 consecutive nodes (scalar loads)
    int deg[4], degp[4];
    const int* row[4];
#pragma unroll
    for (int n = 0; n < 4; ++n) {
        int d = cnt[nb + n];
        int dc = d < 0 ? 0 : (d > CAP ? CAP : d);
        deg[n] = dc;
        int dp = (dc + 15) & ~15;
        degp[n] = dp < 16 ? 16 : dp;
        row[n] = srcs + ((size_t)(nb + n) << 6);
    }
    int cmax = degp[0];
    cmax = degp[1] > cmax ? degp[1] : cmax;
    cmax = degp[2] > cmax ? degp[2] : cmax;
    cmax = degp[3] > cmax ? degp[3] : cmax;

    // ---- self rows (issued alongside the gather burst)
    unsigned us[4];
#pragma unroll
    for (int n = 0; n < 4; ++n) us[n] = xu[(size_t)(nb + n) * 32 + cl];

    float A0[4] = {0.f, 0.f, 0.f, 0.f}, A1[4] = {0.f, 0.f, 0.f, 0.f};
    float B0[4] = {0.f, 0.f, 0.f, 0.f}, B1[4] = {0.f, 0.f, 0.f, 0.f};

    // ---- chunk 0: unconditional for all 4 nodes (rows padded to >=16), 32 loads in flight
    {
        unsigned uv[4][8];
#pragma unroll
        for (int n = 0; n < 4; ++n)
#pragma unroll
            for (int k = 0; k < 8; ++k) {
                int ia = row[n][2 * k] & 0x1FFFF;
                int ib = row[n][2 * k + 1] & 0x1FFFF;
                int idx = half ? ib : ia;
                uv[n][k] = xu[(size_t)idx * 32 + cl];
            }
#pragma unroll
        for (int n = 0; n < 4; ++n)
#pragma unroll
            for (int k = 0; k < 8; ++k) {
                float lo = b2f((unsigned short)(uv[n][k] & 0xFFFF));
                float hi = b2f((unsigned short)(uv[n][k] >> 16));
                if (k & 1) { B0[n] += lo; B1[n] += hi; }
                else       { A0[n] += lo; A1[n] += hi; }
            }
    }

    // ---- remainder chunks: wave-uniform scalar branches, issue-all then consume-all
    for (int c = 16; c < cmax; c += 16) {
        unsigned uc[4][8];
#pragma unroll
        for (int n = 0; n < 4; ++n)
            if (c < degp[n])
#pragma unroll
                for (int k = 0; k < 8; ++k) {
                    int ia = row[n][c + 2 * k] & 0x1FFFF;
                    int ib = row[n][c + 2 * k + 1] & 0x1FFFF;
                    int idx = half ? ib : ia;
                    uc[n][k] = xu[(size_t)idx * 32 + cl];
                }
#pragma unroll
        for (int n = 0; n < 4; ++n)
            if (c < degp[n])
#pragma unroll
                for (int k = 0; k < 8; ++k) {
                    float lo = b2f((unsigned short)(uc[n][k] & 0xFFFF));
                    float hi = b2f((unsigned short)(uc[n][k] >> 16));
                    if (k & 1) { B0[n] += lo; B1[n] += hi; }
                    else       { A0[n] += lo; A1[n] += hi; }
                }
    }

    // ---- reduce + BN affine + pack
#pragma unroll
    for (int n = 0; n < 4; ++n) {
        float S0 = (A0[n] + B0[n]);
        float S1 = (A1[n] + B1[n]);
        S0 += __shfl_xor(S0, 32);
        S1 += __shfl_xor(S1, 32);
        if (half == 0) {
            float selflo = b2f((unsigned short)(us[n] & 0xFFFF));
            float selfhi = b2f((unsigned short)(us[n] >> 16));
            float db = scale + (float)deg[n];
            float v0 = fmaf(a0f, fmaf(scale, selflo, S0), db * b0f);
            float v1 = fmaf(a1f, fmaf(scale, selfhi, S1), db * b1f);
            ((unsigned*)out)[(size_t)(nb + n) * 32 + cl] =
                (unsigned)f2b(v0) | ((unsigned)f2b(v1) << 16);
        }
    }
}

// ---------------- MFMA MLP v10: LDS weights + SREP-32 stats + vectorized writeback ----------------
// R14 confirmed weight staging (-3.4 us/dispatch). v10 attacks the two remaining
// quantified terms: (1) stats atomic chains 1563/SREP per address -> SREP 8->32 cuts
// serialization 195->49 RMWs; (2) writeback 8x dword -> 2x dwordx4 per thread
// (lane>>3 = row-in-wave-tile, lane&7 = granule; inverse of the staging map).

__global__ __launch_bounds__(256, 4) void mlp_kernel(unsigned short* __restrict__ x,
                                                     const unsigned short* __restrict__ whi,
                                                     const unsigned short* __restrict__ wlo,
                                                     const float* __restrict__ bs, int l,
                                                     float* __restrict__ stats,
                                                     const int* __restrict__ graph_ids,
                                                     float* __restrict__ pooled, int last) {
    __shared__ __align__(16) unsigned short xs[64 * 64];    // 8 KB
    __shared__ __align__(16) unsigned short wsh[4096];      // 8 KB: whi[l][mm]
    __shared__ __align__(16) unsigned short wsl[4096];      // 8 KB: wlo[l][mm]
    __shared__ int garr[64];
    __shared__ float ssum[256], sqq[256];
    int t = threadIdx.x;
    int nodebase = blockIdx.x * 64;
    int lane = t & 63, w = t >> 6;
    int m = lane & 15, q = lane >> 4;

    const unsigned short* whil = whi + (size_t)l * 12288;
    const unsigned short* wlol = wlo + (size_t)l * 12288;

    // mm0 A fragments straight from global (issued first; slack rows masked later)
    const unsigned short* xrow = x + (((size_t)(nodebase + w * 16 + m)) << 6);
    short8 a0[2];
#pragma unroll
    for (int kc = 0; kc < 2; ++kc)
        a0[kc] = *(const short8*)&xrow[kc * 32 + q * 8];

    // stage mm0 weights: 16 KB, 64 B/thread, coalesced (layout copied verbatim)
#pragma unroll
    for (int i = 0; i < 2; ++i) {
        int g = (i * 256 + t) * 8;
        *(int4*)&wsh[g] = *(const int4*)&whil[g];
        *(int4*)&wsl[g] = *(const int4*)&wlol[g];
    }

    if (lane < 16) {
        int n = nodebase + w * 16 + lane;
        garr[w * 16 + lane] = (n < N_NODES) ? (graph_ids[n] & (N_GRAPHS - 1)) : -1;
    }
    __syncthreads();   // weights staged

    const float* bb = bs + l * 3 * 64;
    for (int mm = 0; mm < 3; ++mm) {
        // A fragments: direct-global for mm0, LDS (own rows) after
        short8 a[2];
        if (mm == 0) {
#pragma unroll
            for (int kc = 0; kc < 2; ++kc) a[kc] = a0[kc];
        } else {
#pragma unroll
            for (int kc = 0; kc < 2; ++kc)
                a[kc] = *(const short8*)&xs[XSH(w * 16 + m, kc * 4 + q)];
        }

        floatx4 acc[4];
#pragma unroll
        for (int tj = 0; tj < 4; ++tj) {
            float bv = bb[mm * 64 + tj * 16 + m];
            acc[tj] = (floatx4){bv, bv, bv, bv};
        }
        // hi chain (weights from LDS)
#pragma unroll
        for (int kc = 0; kc < 2; ++kc) {
            short8 bh[4];
#pragma unroll
            for (int tj = 0; tj < 4; ++tj)
                bh[tj] = *(const short8*)&wsh[XSH(tj * 16 + m, kc * 4 + q)];
#pragma unroll
            for (int tj = 0; tj < 4; ++tj)
                acc[tj] = __builtin_amdgcn_mfma_f32_16x16x32_bf16(a[kc], bh[tj], acc[tj], 0, 0, 0);
        }
        // lo chain (weights from LDS, same accumulator)
#pragma unroll
        for (int kc = 0; kc < 2; ++kc) {
            short8 bl[4];
#pragma unroll
            for (int tj = 0; tj < 4; ++tj)
                bl[tj] = *(const short8*)&wsl[XSH(tj * 16 + m, kc * 4 + q)];
#pragma unroll
            for (int tj = 0; tj < 4; ++tj)
                acc[tj] = __builtin_amdgcn_mfma_f32_16x16x32_bf16(a[kc], bl[tj], acc[tj], 0, 0, 0);
        }
        // ReLU + write-back (wave-local rows)
#pragma unroll
        for (int tj = 0; tj < 4; ++tj) {
            int col = tj * 16 + m;
#pragma unroll
            for (int r = 0; r < 4; ++r) {
                int row = w * 16 + q * 4 + r;
                float v = acc[tj][r];
                xs[XSH(row, col >> 3) + (col & 7)] = f2b(v > 0.f ? v : 0.f);
            }
        }
        // restage weights for next mm (barrier before overwrite, barrier after)
        if (mm < 2) {
            __syncthreads();
            const unsigned short* nh = whil + ((mm + 1) << 12);
            const unsigned short* nl = wlol + ((mm + 1) << 12);
#pragma unroll
            for (int i = 0; i < 2; ++i) {
                int g = (i * 256 + t) * 8;
                *(int4*)&wsh[g] = *(const int4*)&nh[g];
                *(int4*)&wsl[g] = *(const int4*)&nl[g];
            }
            __syncthreads();
        }
    }

    if (!last) {
        // vectorized writeback: lane owns 16B granule qr of row (w*16 + lane>>3 + it*8)
        int4* xo4 = (int4*)x;
#pragma unroll
        for (int it = 0; it < 2; ++it) {
            int row = w * 16 + (lane >> 3) + it * 8;
            int qr = lane & 7;
            int node = nodebase + row;
            if (node < N_NODES)
                xo4[(size_t)node * 8 + qr] = *(const int4*)&xs[XSH(row, qr)];
        }
    }
    {
        int c = lane;
        float s = 0.f, q2 = 0.f, acc2 = 0.f;
        int cur = -1;
#pragma unroll
        for (int k = 0; k < 16; ++k) {
            int row = w * 16 + k;
            int g = garr[row];
            if (g >= 0) {
                float v = b2f(xs[XSH(row, c >> 3) + (c & 7)]);
                s += v;
                q2 += v * v;
                if (g != cur) {
                    if (cur >= 0) atomicAdd(&pooled[cur * 192 + l * 64 + c], acc2);
                    acc2 = 0.f;
                    cur = g;
                }
                acc2 += v;
            }
        }
        if (cur >= 0) atomicAdd(&pooled[cur * 192 + l * 64 + c], acc2);
        ssum[t] = s;
        sqq[t] = q2;
    }
    __syncthreads();
    if (t < 64) {
        float S = ssum[t] + ssum[t + 64] + ssum[t + 128] + ssum[t + 192];
        float Q = sqq[t] + sqq[t + 64] + sqq[t + 128] + sqq[t + 192];
        float* sp = stats + (blockIdx.x & (SREP - 1)) * SSTRIDE + l * 128;
        atomicAdd(&sp[t], S);
        atomicAdd(&sp[64 + t], Q);
    }
}

// ---------------- final classifier (replica-summed stats) ----------------

__global__ __launch_bounds__(256) void out_kernel(const float* __restrict__ pooled,
                                                  const float* __restrict__ stats,
                                                  const float* __restrict__ gamma,
                                                  const float* __restrict__ beta,
                                                  const int* __restrict__ gs,
                                                  const int* __restrict__ ge,
                                                  const float* __restrict__ Wo,
                                                  const float* __restrict__ bo,
                                                  float* __restrict__ out) {
    __shared__ float sab[384];
    int t = threadIdx.x;
    if (t < 192) {
        int l2 = t / 64, c = t & 63;
        float S = 0.f, Q = 0.f;
#pragma unroll
        for (int rp = 0; rp < SREP; ++rp) {
            S += stats[rp * SSTRIDE + l2 * 128 + c];
            Q += stats[rp * SSTRIDE + l2 * 128 + 64 + c];
        }
        float mean = S * (1.0f / N_NODES);
        float var = Q * (1.0f / N_NODES) - mean * mean;
        float rstd = rsqrtf(var + BN_EPS);
        float a = gamma[l2 * 64 + c] * rstd;
        sab[l2 * 128 + c] = a;
        sab[l2 * 128 + 64 + c] = beta[l2 * 64 + c] - mean * a;
    }
    __syncthreads();
    int idx = blockIdx.x * blockDim.x + t;
    if (idx < N_GRAPHS * NUM_CLASSES) {
        int g = idx / NUM_CLASSES, k = idx % NUM_CLASSES;
        float cg = (float)(ge[g] - gs[g]);
        float acc = bo[k];
        for (int l2 = 0; l2 < 3; ++l2)
            for (int c = 0; c < 64; ++c) {
                float gf = fmaf(sab[l2 * 128 + c], pooled[g * 192 + l2 * 64 + c],
                                sab[l2 * 128 + 64 + c] * cg);
                acc = fmaf(gf, Wo[(l2 * 64 + c) * NUM_CLASSES + k], acc);
            }
        out[idx] = acc;
    }
}

extern "C" void kernel_launch(void* const* d_in, const int* in_sizes, int n_in,
                              void* d_out, int out_size, void* d_ws, size_t ws_size,
                              hipStream_t stream) {
    const int*   node_ids  = (const int*)d_in[0];
    const int*   edge_src  = (const int*)d_in[1];
    const int*   edge_dst  = (const int*)d_in[2];
    const int*   graph_ids = (const int*)d_in[3];
    const float* emb       = (const float*)d_in[4];
    const float* Ws        = (const float*)d_in[5];
    const float* bs        = (const float*)d_in[6];
    const float* gamma     = (const float*)d_in[7];
    const float* beta      = (const float*)d_in[8];
    const float* eps       = (const float*)d_in[9];
    const float* W_out     = (const float*)d_in[10];
    const float* b_out     = (const float*)d_in[11];
    float* out = (float*)d_out;

    // workspace
    unsigned short* h    = (unsigned short*)d_ws;         // 6,400,000 sh (+8192 slack)
    unsigned short* xin  = h + 6400000 + 8192;            // 6,400,000 sh (+8192 slack)
    unsigned short* whi  = xin + 6400000 + 8192;          // 36,864 sh
    unsigned short* wlo  = whi + 36864;                   // 36,864 sh
    int*   srcs   = (int*)(wlo + 36864);                  // 6,400,000 i (padded CSR)
    int*   rec    = srcs + 6400000;                       // NUSED*BCAP i
    float* pooled = (float*)(rec + NUSED * BCAP);         // 98,304 f
    float* stats  = pooled + 98304;                       // SREP*SSTRIDE = 12,288 f
    int*   cnt    = (int*)(stats + SREP * SSTRIDE);       // 100,000 i
    int*   gs     = cnt + 100000;                         // 512 i
    int*   ge     = gs + 512;                             // 512 i
    int*   cursor = ge + 512;                             // 256 i (bucket totals)

    // only gs/ge/cursor need host-side zero; pooled/stats/cnt zeroed inside prep.
    hipMemsetAsync(gs, 0, (size_t)(512 + 512 + 256) * 4, stream);

    prep_kernel<<<CBLK + WPBLK + EMBBLK + ZBLK, 1024, 0, stream>>>(
        edge_src, edge_dst, cursor, rec, Ws, whi, wlo,
        node_ids, graph_ids, emb, h, xin, gs, ge, (unsigned*)pooled);
    fill_kernel<<<NUSED, 1024, 0, stream>>>(rec, cursor, cnt, srcs);

    const int MLP_BLK = (N_NODES + 63) / 64;   // 1563
    const int AGG_BLK = N_NODES / 16;          // 6250 blocks * 4 waves * 4 nodes
    for (int l = 0; l < 3; ++l) {
        unsigned short* X = (l % 2 == 0) ? h : xin;
        unsigned short* A = (l % 2 == 0) ? xin : h;
        agg_kernel<<<AGG_BLK, 256, 0, stream>>>(X, cnt, srcs, eps, l, stats, gamma, beta, A);
        mlp_kernel<<<MLP_BLK, 256, 0, stream>>>(A, whi, wlo, bs, l, stats, graph_ids, pooled, l == 2);
    }

    out_kernel<<<(N_GRAPHS * NUM_CLASSES + 255) / 256, 256, 0, stream>>>(
        pooled, stats, gamma, beta, gs, ge, W_out, b_out, out);
}

// Round 16
// 285.447 us; speedup vs baseline: 1.1901x; 1.1901x over previous
//
#include <hip/hip_runtime.h>

#define N_NODES 100000
#define N_EDGES 1600000
#define N_GRAPHS 512
#define HID 64
#define NUM_CLASSES 100
#define ID_OFFSET 1500
#define BN_EPS 1e-5f
#define CAP 64
#define NBKT 256
#define BSHIFT 9
#define NUSED ((N_NODES + 511) >> 9)   // 196 buckets of 512 nodes
#define BCAP 10240                      // per-bucket record capacity
#define CBLK 98
#define CHUNK 16384
#define WPBLK 5                         // wprep blocks inside prep_kernel
#define EMBBLK ((N_NODES * 32 + 1023) / 1024)   // 3125
#define SREP 8                          // stats atomic replicas (8 = proven agg-safe; 32 poisoned agg VGPR, R15)
#define SSTRIDE 384                     // floats per stats replica
#define ZWORDS (98304 + SREP * SSTRIDE + 100000)  // pooled + stats + cnt (4B words)
#define ZBLK ((ZWORDS + 1023) / 1024)   // zero blocks inside prep
#define DUMMY_ROW 100000                // zeroed row in x-buffer slack, pad target

typedef __attribute__((ext_vector_type(8))) short short8;
typedef __attribute__((ext_vector_type(4))) float floatx4;

__device__ __forceinline__ float b2f(unsigned short u) {
    return __builtin_bit_cast(float, ((unsigned)u) << 16);
}
__device__ __forceinline__ unsigned short f2b(float f) {   // RNE
    unsigned x = __builtin_bit_cast(unsigned, f);
    x += 0x7FFFu + ((x >> 16) & 1u);
    return (unsigned short)(x >> 16);
}

// swizzled granule layout: 16-row tiles, 8 granules(16B)/row, granule slot = (row&15)^q
#define XSH(row, qq) ((((((row) >> 4) << 7) + ((qq) << 4) + (((row) & 15) ^ (qq))) * 8))

// ---------------- fused prep: binning + wprep + embed + workspace zero ----------------

__global__ __launch_bounds__(1024) void prep_kernel(const int* __restrict__ src,
                                                    const int* __restrict__ dst,
                                                    int* __restrict__ cursor,
                                                    int* __restrict__ rec,
                                                    const float* __restrict__ Ws,
                                                    unsigned short* __restrict__ whi,
                                                    unsigned short* __restrict__ wlo,
                                                    const int* __restrict__ node_ids,
                                                    const int* __restrict__ gid,
                                                    const float* __restrict__ emb,
                                                    unsigned short* __restrict__ h,
                                                    unsigned short* __restrict__ xin,
                                                    int* __restrict__ gs,
                                                    int* __restrict__ ge,
                                                    unsigned* __restrict__ zbase) {
    __shared__ int hist[NBKT];
    __shared__ int base_s[NBKT];
    int t = threadIdx.x;
    int blk = blockIdx.x;

    if (blk < CBLK) {
        // ---- dummy-row zeroing piggybacked on block 0 (replaces 2 memset launches)
        if (blk == 0 && t < 32) {
            ((unsigned*)(h + (size_t)DUMMY_ROW * 64))[t] = 0u;
            ((unsigned*)(xin + (size_t)DUMMY_ROW * 64))[t] = 0u;
        }
        // ---- edge binning (one pass) ----
        if (t < NBKT) hist[t] = 0;
        __syncthreads();
        int cb = blk * CHUNK;
        int d_[16], s_[16];
#pragma unroll
        for (int k = 0; k < 16; ++k) {
            int i = cb + k * 1024 + t;
            d_[k] = (i < N_EDGES) ? dst[i] : -1;
            s_[k] = (i < N_EDGES) ? src[i] : 0;
            if (d_[k] >= 0) atomicAdd(&hist[((unsigned)d_[k] >> BSHIFT) & (NBKT - 1)], 1);
        }
        __syncthreads();
        if (t < NBKT) base_s[t] = (hist[t] > 0) ? atomicAdd(&cursor[t], hist[t]) : 0;
        __syncthreads();
        if (t < NBKT) hist[t] = 0;
        __syncthreads();
#pragma unroll
        for (int k = 0; k < 16; ++k) {
            if (d_[k] >= 0) {
                unsigned d = (unsigned)d_[k];
                int b = (d >> BSHIFT) & (NBKT - 1);
                int p = atomicAdd(&hist[b], 1);
                int g = base_s[b] + p;
                if ((unsigned)g < BCAP)
                    rec[b * BCAP + g] = ((int)(d & 511) << 17) | (s_[k] & 0x1FFFF);
            }
        }
    } else if (blk < CBLK + WPBLK) {
        // ---- W pre-convert + pre-swizzle, hi/lo split ----
        int G = (blk - CBLK) * 1024 + t;
        if (G < 3 * 1536) {
            int l = G / 1536, Gp = G % 1536;
            int mm = Gp >> 9, rem = Gp & 511;
            int kq = rem >> 6, n = rem & 63;
            const float* Wp = Ws + l * 12288 + mm * 4096 + (kq * 8) * 64 + n;
            unsigned short uh[8], ul[8];
#pragma unroll
            for (int j = 0; j < 8; ++j) {
                float w = Wp[j * 64];
                unsigned short hi = f2b(w);
                uh[j] = hi;
                ul[j] = f2b(w - b2f(hi));
            }
            size_t off = (size_t)l * 12288 + (mm << 12) + XSH(n, kq);
            *(short8*)&whi[off] = *(short8*)uh;
            *(short8*)&wlo[off] = *(short8*)ul;
        }
    } else if (blk < CBLK + WPBLK + EMBBLK) {
        // ---- embedding gather (bf16) + sorted-graph span boundaries ----
        int idx = (blk - CBLK - WPBLK) * 1024 + t;
        if (idx < N_NODES * 32) {
            int n = idx >> 5, cp = idx & 31;
            const float2 e = *(const float2*)(emb + (((size_t)(node_ids[n] + ID_OFFSET)) << 6) + cp * 2);
            unsigned v = (unsigned)f2b(e.x) | ((unsigned)f2b(e.y) << 16);
            ((unsigned*)h)[n * 32 + cp] = v;
            if (cp == 0) {
                int g = gid[n] & (N_GRAPHS - 1);
                if (n == 0 || (gid[n - 1] & (N_GRAPHS - 1)) != g) gs[g] = n;
                if (n == N_NODES - 1 || (gid[n + 1] & (N_GRAPHS - 1)) != g) ge[g] = n + 1;
            }
        }
    } else {
        // ---- zero pooled + stats + cnt (consumers run in later kernels)
        int idx = (blk - CBLK - WPBLK - EMBBLK) * 1024 + t;
        if (idx < ZWORDS) zbase[idx] = 0u;
    }
}

// ---------------- per-bucket CSR fill (block-parallel pad to multiple of 16) ----------------

__global__ __launch_bounds__(1024) void fill_kernel(const int* __restrict__ rec,
                                                    const int* __restrict__ cursor,
                                                    int* __restrict__ cnt,
                                                    int* __restrict__ srcs) {
    __shared__ int lcnt[512];
    int t = threadIdx.x;
    int b = blockIdx.x;            // 0..NUSED-1
    if (t < 512) lcnt[t] = 0;
    __syncthreads();
    int nb = cursor[b];
    if (nb < 0) nb = 0;
    if (nb > BCAP) nb = BCAP;
    const int* seg = rec + b * BCAP;
    for (int i = t; i < nb; i += 1024) {
        unsigned r = (unsigned)seg[i];
        int dl = (int)((r >> 17) & 511);
        int s = (int)(r & 0x1FFFF);
        int node = (b << BSHIFT) + dl;
        int p = atomicAdd(&lcnt[dl], 1);
        if (p < CAP && node < N_NODES) srcs[(node << 6) + p] = s;
    }
    __syncthreads();
    if (t < 512) {
        int node = (b << BSHIFT) + t;
        if (node < N_NODES) cnt[node] = lcnt[t];
    }
    __syncthreads();
    // block-parallel padding: slot p of node nl gets DUMMY if degc <= p < degp
    for (int i = t; i < 512 * 64; i += 1024) {
        int nl = i >> 6, p = i & 63;
        int node = (b << BSHIFT) + nl;
        if (node < N_NODES) {
            int deg = lcnt[nl];
            int degc = deg > CAP ? CAP : deg;
            int degp = (degc + 15) & ~15;
            if (degp < 16) degp = 16;
            if (p >= degc && p < degp) srcs[(node << 6) + p] = DUMMY_ROW;
        }
    }
}

// ---------------- GIN aggregation (frozen: proven 2.15 TB/s; SREP-8 BN sum) ----------------

__global__ __launch_bounds__(256) void agg_kernel(const unsigned short* __restrict__ x,
                                                  const int* __restrict__ cnt,
                                                  const int* __restrict__ srcs,
                                                  const float* __restrict__ eps, int l,
                                                  const float* __restrict__ stats,
                                                  const float* __restrict__ gamma,
                                                  const float* __restrict__ beta,
                                                  unsigned short* __restrict__ out) {
    int nb = __builtin_amdgcn_readfirstlane(((blockIdx.x << 2) + (threadIdx.x >> 6)) << 2);
    int lane = threadIdx.x & 63;
    int half = lane >> 5;
    int cl = lane & 31;
    const unsigned* __restrict__ xu = (const unsigned*)x;

    // ---- BN coefficients for layer l-1 (replica-summed), prefetched early
    float scale = 1.0f + eps[l];
    float a0f = 1.0f, a1f = 1.0f, b0f = 0.0f, b1f = 0.0f;
    if (l > 0) {
        int lp = l - 1;
        float sm0 = 0.f, sm1 = 0.f, sq0 = 0.f, sq1 = 0.f;
#pragma unroll
        for (int rp = 0; rp < SREP; ++rp) {
            const float* sp = stats + rp * SSTRIDE + lp * 128;
            float2 a_ = *(const float2*)&sp[2 * cl];
            float2 b_ = *(const float2*)&sp[64 + 2 * cl];
            sm0 += a_.x; sm1 += a_.y;
            sq0 += b_.x; sq1 += b_.y;
        }
        float2 gm = *(const float2*)&gamma[lp * 64 + 2 * cl];
        float2 bt = *(const float2*)&beta[lp * 64 + 2 * cl];
        float mean0 = sm0 * (1.0f / N_NODES);
        float var0 = sq0 * (1.0f / N_NODES) - mean0 * mean0;
        float r0 = rsqrtf(var0 + BN_EPS);
        a0f = gm.x * r0;
        b0f = bt.x - mean0 * a0f;
        float mean1 = sm1 * (1.0f / N_NODES);
        float var1 = sq1 * (1.0f / N_NODES) - mean1 * mean1;
        float r1 = rsqrtf(var1 + BN_EPS);
        a1f = gm.y * r1;
        b1f = bt.y - mean1 * a1f;
    }

    // ---- degrees + row pointers for 4 consecutive nodes (scalar loads)
    int deg[4], degp[4];
    const int* row[4];
#pragma unroll
    for (int n = 0; n < 4; ++n) {
        int d = cnt[nb + n];
        int dc = d < 0 ? 0 : (d > CAP ? CAP : d);
        deg[n] = dc;
        int dp = (dc + 15) & ~15;
        degp[n] = dp < 16 ? 16 : dp;
        row[n] = srcs + ((size_t)(nb + n) << 6);
    }
    int cmax = degp[0];
    cmax = degp[1] > cmax ? degp[1] : cmax;
    cmax = degp[2] > cmax ? degp[2] : cmax;
    cmax = degp[3] > cmax ? degp[3] : cmax;

    // ---- self rows (issued alongside the gather burst)
    unsigned us[4];
#pragma unroll
    for (int n = 0; n < 4; ++n) us[n] = xu[(size_t)(nb + n) * 32 + cl];

    float A0[4] = {0.f, 0.f, 0.f, 0.f}, A1[4] = {0.f, 0.f, 0.f, 0.f};
    float B0[4] = {0.f, 0.f, 0.f, 0.f}, B1[4] = {0.f, 0.f, 0.f, 0.f};

    // ---- chunk 0: unconditional for all 4 nodes (rows padded to >=16), 32 loads in flight
    {
        unsigned uv[4][8];
#pragma unroll
        for (int n = 0; n < 4; ++n)
#pragma unroll
            for (int k = 0; k < 8; ++k) {
                int ia = row[n][2 * k] & 0x1FFFF;
                int ib = row[n][2 * k + 1] & 0x1FFFF;
                int idx = half ? ib : ia;
                uv[n][k] = xu[(size_t)idx * 32 + cl];
            }
#pragma unroll
        for (int n = 0; n < 4; ++n)
#pragma unroll
            for (int k = 0; k < 8; ++k) {
                float lo = b2f((unsigned short)(uv[n][k] & 0xFFFF));
                float hi = b2f((unsigned short)(uv[n][k] >> 16));
                if (k & 1) { B0[n] += lo; B1[n] += hi; }
                else       { A0[n] += lo; A1[n] += hi; }
            }
    }

    // ---- remainder chunks: wave-uniform scalar branches, issue-all then consume-all
    for (int c = 16; c < cmax; c += 16) {
        unsigned uc[4][8];
#pragma unroll
        for (int n = 0; n < 4; ++n)
            if (c < degp[n])
#pragma unroll
                for (int k = 0; k < 8; ++k) {
                    int ia = row[n][c + 2 * k] & 0x1FFFF;
                    int ib = row[n][c + 2 * k + 1] & 0x1FFFF;
                    int idx = half ? ib : ia;
                    uc[n][k] = xu[(size_t)idx * 32 + cl];
                }
#pragma unroll
        for (int n = 0; n < 4; ++n)
            if (c < degp[n])
#pragma unroll
                for (int k = 0; k < 8; ++k) {
                    float lo = b2f((unsigned short)(uc[n][k] & 0xFFFF));
                    float hi = b2f((unsigned short)(uc[n][k] >> 16));
                    if (k & 1) { B0[n] += lo; B1[n] += hi; }
                    else       { A0[n] += lo; A1[n] += hi; }
                }
    }

    // ---- reduce + BN affine + pack
#pragma unroll
    for (int n = 0; n < 4; ++n) {
        float S0 = (A0[n] + B0[n]);
        float S1 = (A1[n] + B1[n]);
        S0 += __shfl_xor(S0, 32);
        S1 += __shfl_xor(S1, 32);
        if (half == 0) {
            float selflo = b2f((unsigned short)(us[n] & 0xFFFF));
            float selfhi = b2f((unsigned short)(us[n] >> 16));
            float db = scale + (float)deg[n];
            float v0 = fmaf(a0f, fmaf(scale, selflo, S0), db * b0f);
            float v1 = fmaf(a1f, fmaf(scale, selfhi, S1), db * b1f);
            ((unsigned*)out)[(size_t)(nb + n) * 32 + cl] =
                (unsigned)f2b(v0) | ((unsigned)f2b(v1) << 16);
        }
    }
}

// ---------------- MFMA MLP v11: LDS weights (R14) + vectorized writeback (R15 keeper) ----------------
// R15 autopsy: SREP=32 poisoned AGG (BN loop 32-iter -> VGPR 40 -> burst serialized,
// +28us/dispatch). Revert SREP to 8; keep only the mlp dwordx4 writeback from R15.
// This is otherwise the best-measured R14 kernel (288.6 us).

__global__ __launch_bounds__(256, 4) void mlp_kernel(unsigned short* __restrict__ x,
                                                     const unsigned short* __restrict__ whi,
                                                     const unsigned short* __restrict__ wlo,
                                                     const float* __restrict__ bs, int l,
                                                     float* __restrict__ stats,
                                                     const int* __restrict__ graph_ids,
                                                     float* __restrict__ pooled, int last) {
    __shared__ __align__(16) unsigned short xs[64 * 64];    // 8 KB
    __shared__ __align__(16) unsigned short wsh[4096];      // 8 KB: whi[l][mm]
    __shared__ __align__(16) unsigned short wsl[4096];      // 8 KB: wlo[l][mm]
    __shared__ int garr[64];
    __shared__ float ssum[256], sqq[256];
    int t = threadIdx.x;
    int nodebase = blockIdx.x * 64;
    int lane = t & 63, w = t >> 6;
    int m = lane & 15, q = lane >> 4;

    const unsigned short* whil = whi + (size_t)l * 12288;
    const unsigned short* wlol = wlo + (size_t)l * 12288;

    // mm0 A fragments straight from global (issued first; slack rows masked later)
    const unsigned short* xrow = x + (((size_t)(nodebase + w * 16 + m)) << 6);
    short8 a0[2];
#pragma unroll
    for (int kc = 0; kc < 2; ++kc)
        a0[kc] = *(const short8*)&xrow[kc * 32 + q * 8];

    // stage mm0 weights: 16 KB, 64 B/thread, coalesced (layout copied verbatim)
#pragma unroll
    for (int i = 0; i < 2; ++i) {
        int g = (i * 256 + t) * 8;
        *(int4*)&wsh[g] = *(const int4*)&whil[g];
        *(int4*)&wsl[g] = *(const int4*)&wlol[g];
    }

    if (lane < 16) {
        int n = nodebase + w * 16 + lane;
        garr[w * 16 + lane] = (n < N_NODES) ? (graph_ids[n] & (N_GRAPHS - 1)) : -1;
    }
    __syncthreads();   // weights staged

    const float* bb = bs + l * 3 * 64;
    for (int mm = 0; mm < 3; ++mm) {
        // A fragments: direct-global for mm0, LDS (own rows) after
        short8 a[2];
        if (mm == 0) {
#pragma unroll
            for (int kc = 0; kc < 2; ++kc) a[kc] = a0[kc];
        } else {
#pragma unroll
            for (int kc = 0; kc < 2; ++kc)
                a[kc] = *(const short8*)&xs[XSH(w * 16 + m, kc * 4 + q)];
        }

        floatx4 acc[4];
#pragma unroll
        for (int tj = 0; tj < 4; ++tj) {
            float bv = bb[mm * 64 + tj * 16 + m];
            acc[tj] = (floatx4){bv, bv, bv, bv};
        }
        // hi chain (weights from LDS)
#pragma unroll
        for (int kc = 0; kc < 2; ++kc) {
            short8 bh[4];
#pragma unroll
            for (int tj = 0; tj < 4; ++tj)
                bh[tj] = *(const short8*)&wsh[XSH(tj * 16 + m, kc * 4 + q)];
#pragma unroll
            for (int tj = 0; tj < 4; ++tj)
                acc[tj] = __builtin_amdgcn_mfma_f32_16x16x32_bf16(a[kc], bh[tj], acc[tj], 0, 0, 0);
        }
        // lo chain (weights from LDS, same accumulator)
#pragma unroll
        for (int kc = 0; kc < 2; ++kc) {
            short8 bl[4];
#pragma unroll
            for (int tj = 0; tj < 4; ++tj)
                bl[tj] = *(const short8*)&wsl[XSH(tj * 16 + m, kc * 4 + q)];
#pragma unroll
            for (int tj = 0; tj < 4; ++tj)
                acc[tj] = __builtin_amdgcn_mfma_f32_16x16x32_bf16(a[kc], bl[tj], acc[tj], 0, 0, 0);
        }
        // ReLU + write-back (wave-local rows)
#pragma unroll
        for (int tj = 0; tj < 4; ++tj) {
            int col = tj * 16 + m;
#pragma unroll
            for (int r = 0; r < 4; ++r) {
                int row = w * 16 + q * 4 + r;
                float v = acc[tj][r];
                xs[XSH(row, col >> 3) + (col & 7)] = f2b(v > 0.f ? v : 0.f);
            }
        }
        // restage weights for next mm (barrier before overwrite, barrier after)
        if (mm < 2) {
            __syncthreads();
            const unsigned short* nh = whil + ((mm + 1) << 12);
            const unsigned short* nl = wlol + ((mm + 1) << 12);
#pragma unroll
            for (int i = 0; i < 2; ++i) {
                int g = (i * 256 + t) * 8;
                *(int4*)&wsh[g] = *(const int4*)&nh[g];
                *(int4*)&wsl[g] = *(const int4*)&nl[g];
            }
            __syncthreads();
        }
    }

    if (!last) {
        // vectorized writeback: lane owns 16B granule qr of row (w*16 + lane>>3 + it*8)
        int4* xo4 = (int4*)x;
#pragma unroll
        for (int it = 0; it < 2; ++it) {
            int row = w * 16 + (lane >> 3) + it * 8;
            int qr = lane & 7;
            int node = nodebase + row;
            if (node < N_NODES)
                xo4[(size_t)node * 8 + qr] = *(const int4*)&xs[XSH(row, qr)];
        }
    }
    {
        int c = lane;
        float s = 0.f, q2 = 0.f, acc2 = 0.f;
        int cur = -1;
#pragma unroll
        for (int k = 0; k < 16; ++k) {
            int row = w * 16 + k;
            int g = garr[row];
            if (g >= 0) {
                float v = b2f(xs[XSH(row, c >> 3) + (c & 7)]);
                s += v;
                q2 += v * v;
                if (g != cur) {
                    if (cur >= 0) atomicAdd(&pooled[cur * 192 + l * 64 + c], acc2);
                    acc2 = 0.f;
                    cur = g;
                }
                acc2 += v;
            }
        }
        if (cur >= 0) atomicAdd(&pooled[cur * 192 + l * 64 + c], acc2);
        ssum[t] = s;
        sqq[t] = q2;
    }
    __syncthreads();
    if (t < 64) {
        float S = ssum[t] + ssum[t + 64] + ssum[t + 128] + ssum[t + 192];
        float Q = sqq[t] + sqq[t + 64] + sqq[t + 128] + sqq[t + 192];
        float* sp = stats + (blockIdx.x & (SREP - 1)) * SSTRIDE + l * 128;
        atomicAdd(&sp[t], S);
        atomicAdd(&sp[64 + t], Q);
    }
}

// ---------------- final classifier (replica-summed stats) ----------------

__global__ __launch_bounds__(256) void out_kernel(const float* __restrict__ pooled,
                                                  const float* __restrict__ stats,
                                                  const float* __restrict__ gamma,
                                                  const float* __restrict__ beta,
                                                  const int* __restrict__ gs,
                                                  const int* __restrict__ ge,
                                                  const float* __restrict__ Wo,
                                                  const float* __restrict__ bo,
                                                  float* __restrict__ out) {
    __shared__ float sab[384];
    int t = threadIdx.x;
    if (t < 192) {
        int l2 = t / 64, c = t & 63;
        float S = 0.f, Q = 0.f;
#pragma unroll
        for (int rp = 0; rp < SREP; ++rp) {
            S += stats[rp * SSTRIDE + l2 * 128 + c];
            Q += stats[rp * SSTRIDE + l2 * 128 + 64 + c];
        }
        float mean = S * (1.0f / N_NODES);
        float var = Q * (1.0f / N_NODES) - mean * mean;
        float rstd = rsqrtf(var + BN_EPS);
        float a = gamma[l2 * 64 + c] * rstd;
        sab[l2 * 128 + c] = a;
        sab[l2 * 128 + 64 + c] = beta[l2 * 64 + c] - mean * a;
    }
    __syncthreads();
    int idx = blockIdx.x * blockDim.x + t;
    if (idx < N_GRAPHS * NUM_CLASSES) {
        int g = idx / NUM_CLASSES, k = idx % NUM_CLASSES;
        float cg = (float)(ge[g] - gs[g]);
        float acc = bo[k];
        for (int l2 = 0; l2 < 3; ++l2)
            for (int c = 0; c < 64; ++c) {
                float gf = fmaf(sab[l2 * 128 + c], pooled[g * 192 + l2 * 64 + c],
                                sab[l2 * 128 + 64 + c] * cg);
                acc = fmaf(gf, Wo[(l2 * 64 + c) * NUM_CLASSES + k], acc);
            }
        out[idx] = acc;
    }
}

extern "C" void kernel_launch(void* const* d_in, const int* in_sizes, int n_in,
                              void* d_out, int out_size, void* d_ws, size_t ws_size,
                              hipStream_t stream) {
    const int*   node_ids  = (const int*)d_in[0];
    const int*   edge_src  = (const int*)d_in[1];
    const int*   edge_dst  = (const int*)d_in[2];
    const int*   graph_ids = (const int*)d_in[3];
    const float* emb       = (const float*)d_in[4];
    const float* Ws        = (const float*)d_in[5];
    const float* bs        = (const float*)d_in[6];
    const float* gamma     = (const float*)d_in[7];
    const float* beta      = (const float*)d_in[8];
    const float* eps       = (const float*)d_in[9];
    const float* W_out     = (const float*)d_in[10];
    const float* b_out     = (const float*)d_in[11];
    float* out = (float*)d_out;

    // workspace
    unsigned short* h    = (unsigned short*)d_ws;         // 6,400,000 sh (+8192 slack)
    unsigned short* xin  = h + 6400000 + 8192;            // 6,400,000 sh (+8192 slack)
    unsigned short* whi  = xin + 6400000 + 8192;          // 36,864 sh
    unsigned short* wlo  = whi + 36864;                   // 36,864 sh
    int*   srcs   = (int*)(wlo + 36864);                  // 6,400,000 i (padded CSR)
    int*   rec    = srcs + 6400000;                       // NUSED*BCAP i
    float* pooled = (float*)(rec + NUSED * BCAP);         // 98,304 f
    float* stats  = pooled + 98304;                       // SREP*SSTRIDE = 3,072 f
    int*   cnt    = (int*)(stats + SREP * SSTRIDE);       // 100,000 i
    int*   gs     = cnt + 100000;                         // 512 i
    int*   ge     = gs + 512;                             // 512 i
    int*   cursor = ge + 512;                             // 256 i (bucket totals)

    // only gs/ge/cursor need host-side zero; pooled/stats/cnt zeroed inside prep.
    hipMemsetAsync(gs, 0, (size_t)(512 + 512 + 256) * 4, stream);

    prep_kernel<<<CBLK + WPBLK + EMBBLK + ZBLK, 1024, 0, stream>>>(
        edge_src, edge_dst, cursor, rec, Ws, whi, wlo,
        node_ids, graph_ids, emb, h, xin, gs, ge, (unsigned*)pooled);
    fill_kernel<<<NUSED, 1024, 0, stream>>>(rec, cursor, cnt, srcs);

    const int MLP_BLK = (N_NODES + 63) / 64;   // 1563
    const int AGG_BLK = N_NODES / 16;          // 6250 blocks * 4 waves * 4 nodes
    for (int l = 0; l < 3; ++l) {
        unsigned short* X = (l % 2 == 0) ? h : xin;
        unsigned short* A = (l % 2 == 0) ? xin : h;
        agg_kernel<<<AGG_BLK, 256, 0, stream>>>(X, cnt, srcs, eps, l, stats, gamma, beta, A);
        mlp_kernel<<<MLP_BLK, 256, 0, stream>>>(A, whi, wlo, bs, l, stats, graph_ids, pooled, l == 2);
    }

    out_kernel<<<(N_GRAPHS * NUM_CLASSES + 255) / 256, 256, 0, stream>>>(
        pooled, stats, gamma, beta, gs, ge, W_out, b_out, out);
}